// Round 2
// baseline (69.277 us; speedup 1.0000x reference)
//
#include <hip/hip_runtime.h>
#include <math.h>

#define B_ 4
#define C_ 2048
#define T_ 8192
#define NW 16            // waves per block
#define ROWS (C_ / NW)   // 128 rows per thread

// Block: 1024 threads = 64 t-columns (lanes) x 16 C-chunks (waves).
// Inner loop is label-free (pure online log2-lse, 4 independent chains);
// the additive margin is applied post-hoc via a single label-logit gather
// and an algebraic fixup. Last finishing block computes the final scalar.
__global__ __launch_bounds__(1024, 8)
void adms_fused(const float* __restrict__ logits,
                const int* __restrict__ target,
                float* __restrict__ accum,   // ws: [0..3] sums, [4..7] counts
                unsigned* __restrict__ done, // ws: counter
                float* __restrict__ out,
                int nblocks)
{
    constexpr float K   = 30.0f * 1.4426950408889634f;         // S*log2(e)
    constexpr float MM  = 30.0f * 0.4f * 1.4426950408889634f;  // S*M*log2(e)
    constexpr float LN2 = 0.6931471805599453f;

    const int tl = threadIdx.x & 63;
    const int w  = threadIdx.x >> 6;
    const int b  = blockIdx.x >> 7;                 // 128 t-tiles per b
    const int t  = ((blockIdx.x & 127) << 6) + tl;

    const float* col = logits + ((size_t)b * C_) * (size_t)T_ + (size_t)t;
    const float* p   = col + (size_t)(w * ROWS) * (size_t)T_;

    float m0=-INFINITY, m1=-INFINITY, m2=-INFINITY, m3=-INFINITY;
    float s0=0.f, s1=0.f, s2=0.f, s3=0.f;

    #pragma unroll 2
    for (int it = 0; it < ROWS / 4; ++it) {
        float x0 = p[0]              * K;
        float x1 = p[(size_t)T_]     * K;
        float x2 = p[(size_t)2 * T_] * K;
        float x3 = p[(size_t)3 * T_] * K;
        p += (size_t)4 * T_;
        float n;
        n = fmaxf(m0, x0); s0 = fmaf(s0, exp2f(m0 - n), exp2f(x0 - n)); m0 = n;
        n = fmaxf(m1, x1); s1 = fmaf(s1, exp2f(m1 - n), exp2f(x1 - n)); m1 = n;
        n = fmaxf(m2, x2); s2 = fmaf(s2, exp2f(m2 - n), exp2f(x2 - n)); m2 = n;
        n = fmaxf(m3, x3); s3 = fmaf(s3, exp2f(m3 - n), exp2f(x3 - n)); m3 = n;
    }
    float ma = fmaxf(fmaxf(m0, m1), fmaxf(m2, m3));
    float sa = fmaf(s0, exp2f(m0 - ma),
               fmaf(s1, exp2f(m1 - ma),
               fmaf(s2, exp2f(m2 - ma), s3 * exp2f(m3 - ma))));

    __shared__ float lds_m[NW][64];
    __shared__ float lds_s[NW][64];
    lds_m[w][tl] = ma;
    lds_s[w][tl] = sa;
    __syncthreads();

    if (w == 0) {
        float M = lds_m[0][tl];
        #pragma unroll
        for (int k = 1; k < NW; ++k) M = fmaxf(M, lds_m[k][tl]);
        float S = 0.f;
        #pragma unroll
        for (int k = 0; k < NW; ++k) S = fmaf(lds_s[k][tl], exp2f(lds_m[k][tl] - M), S);

        const int raw   = target[b * T_ + t];
        const bool valid = (raw != -1);
        const int lbl   = valid ? raw : 0;
        const float xlp = col[(size_t)lbl * T_] * K;        // plain label logit
        // swap exp2(xlp) term for exp2(xlp - MM)
        float Smod = S - exp2f(xlp - M) + exp2f(xlp - MM - M);
        Smod = fmaxf(Smod, 1e-30f);
        const float lse2 = M + log2f(Smod);
        const float L = (xlp - MM - lse2) * LN2;

        float contrib = valid ? -L : 0.f;
        #pragma unroll
        for (int off = 32; off; off >>= 1) contrib += __shfl_down(contrib, off);
        const unsigned long long vm = __ballot(valid);

        if (tl == 0) {
            atomicAdd(&accum[b], contrib);
            atomicAdd(&accum[4 + b], (float)__popcll(vm));
            __threadfence();
            const unsigned old = atomicAdd(done, 1u);
            if (old == (unsigned)(nblocks - 1)) {
                float acc = 0.f;
                #pragma unroll
                for (int bb = 0; bb < B_; ++bb) {
                    const float ssum = atomicAdd(&accum[bb], 0.f);     // coherent read
                    const float scnt = atomicAdd(&accum[4 + bb], 0.f);
                    acc += ssum / scnt;
                }
                out[0] = acc * 0.25f;
            }
        }
    }
}

extern "C" void kernel_launch(void* const* d_in, const int* in_sizes, int n_in,
                              void* d_out, int out_size, void* d_ws, size_t ws_size,
                              hipStream_t stream) {
    const float* logits = (const float*)d_in[0];
    const int*   target = (const int*)d_in[1];
    float*    out   = (float*)d_out;
    float*    accum = (float*)d_ws;
    unsigned* done  = (unsigned*)((char*)d_ws + 8 * sizeof(float));

    hipMemsetAsync(d_ws, 0, 8 * sizeof(float) + sizeof(unsigned), stream);
    const int nblocks = B_ * (T_ / 64);   // 512
    adms_fused<<<nblocks, 1024, 0, stream>>>(logits, target, accum, done, out, nblocks);
}

// Round 3
// 61.839 us; speedup vs baseline: 1.1203x; 1.1203x over previous
//
#include <hip/hip_runtime.h>
#include <math.h>

#define B_ 4
#define C_ 2048
#define T_ 8192
#define CS 4                 // C-splits per (b, t-tile)
#define TILE_T 256           // t columns per block = 64 lanes * 4 (float4)
#define NW 8                 // waves per block (512 threads)
#define CROWS (C_ / CS)      // 512 rows per block
#define ROWS_W (CROWS / NW)  // 64 rows per wave/thread

typedef float f4 __attribute__((ext_vector_type(4)));

#define WS_PARTIAL 0
#define NPART (B_ * T_ * CS)                      // 131072 float2 = 1 MiB
#define WS_ACC (NPART * 8)                        // 8 floats
#define WS_DONE (WS_ACC + 8 * 4)                  // 1 uint

constexpr float Kc   = 30.0f * 1.4426950408889634f;          // S*log2(e)
constexpr float MM2  = 30.0f * 0.4f * 1.4426950408889634f;   // S*M*log2(e)
constexpr float LN2f = 0.6931471805599453f;

// K1: per (b, t-tile, c-chunk) partial logsumexp in raw-w domain.
// float4 loads (1KB/wave-instr), 8 rows in flight, group-max update.
__global__ __launch_bounds__(512, 4)
void adms_partial(const float* __restrict__ logits,
                  float2* __restrict__ partial)
{
    const int lane = threadIdx.x & 63;
    const int w    = threadIdx.x >> 6;
    const int blk  = blockIdx.x;
    const int cs = blk & (CS - 1);
    const int tt = (blk >> 2) & 31;
    const int b  = blk >> 7;

    const int t0 = tt * TILE_T + lane * 4;
    const int c0 = cs * CROWS + w * ROWS_W;
    const float* p = logits + (size_t)(b * C_ + c0) * T_ + t0;

    float m[4] = {-INFINITY, -INFINITY, -INFINITY, -INFINITY};
    float s[4] = {0.f, 0.f, 0.f, 0.f};

    for (int r = 0; r < ROWS_W; r += 8) {
        f4 v[8];
        #pragma unroll
        for (int i = 0; i < 8; ++i)
            v[i] = *(const f4*)(p + (size_t)(r + i) * T_);
        #pragma unroll
        for (int j = 0; j < 4; ++j) {
            float g = fmaxf(fmaxf(fmaxf(v[0][j], v[1][j]), fmaxf(v[2][j], v[3][j])),
                            fmaxf(fmaxf(v[4][j], v[5][j]), fmaxf(v[6][j], v[7][j])));
            float gK = g * Kc;
            float e0 = exp2f(fmaf(v[0][j], Kc, -gK));
            float e1 = exp2f(fmaf(v[1][j], Kc, -gK));
            float e2 = exp2f(fmaf(v[2][j], Kc, -gK));
            float e3 = exp2f(fmaf(v[3][j], Kc, -gK));
            float e4 = exp2f(fmaf(v[4][j], Kc, -gK));
            float e5 = exp2f(fmaf(v[5][j], Kc, -gK));
            float e6 = exp2f(fmaf(v[6][j], Kc, -gK));
            float e7 = exp2f(fmaf(v[7][j], Kc, -gK));
            float ps = ((e0 + e1) + (e2 + e3)) + ((e4 + e5) + (e6 + e7));
            float n = fmaxf(m[j], g);
            s[j] = fmaf(s[j], exp2f((m[j] - n) * Kc), ps * exp2f((g - n) * Kc));
            m[j] = n;
        }
    }

    __shared__ float lds_m[NW][64][4];
    __shared__ float lds_s[NW][64][4];
    #pragma unroll
    for (int j = 0; j < 4; ++j) { lds_m[w][lane][j] = m[j]; lds_s[w][lane][j] = s[j]; }
    __syncthreads();

    if (threadIdx.x < TILE_T) {
        const int tc = threadIdx.x;
        const int ls = tc >> 2, j = tc & 3;
        float n = -INFINITY;
        #pragma unroll
        for (int k = 0; k < NW; ++k) n = fmaxf(n, lds_m[k][ls][j]);
        float S = 0.f;
        #pragma unroll
        for (int k = 0; k < NW; ++k)
            S = fmaf(lds_s[k][ls][j], exp2f((lds_m[k][ls][j] - n) * Kc), S);
        partial[((size_t)(b << 13) + tt * TILE_T + tc) * CS + cs] = make_float2(n, S);
    }
}

// K2: merge CS partials per (b,t), gather label logit, margin fixup,
// reduce, last-block finalize.
__global__ __launch_bounds__(512)
void adms_merge(const float* __restrict__ logits,
                const int* __restrict__ target,
                const float2* __restrict__ partial,
                float* __restrict__ accum,
                unsigned* __restrict__ done,
                float* __restrict__ out,
                int nblocks)
{
    const int idx = blockIdx.x * 512 + threadIdx.x;   // 0..32767
    const int b = idx >> 13;
    const int t = idx & (T_ - 1);

    const f4* pf = (const f4*)(partial + (size_t)idx * CS);
    f4 q0 = pf[0];   // m0,s0,m1,s1
    f4 q1 = pf[1];   // m2,s2,m3,s3

    float n = fmaxf(fmaxf(q0[0], q0[2]), fmaxf(q1[0], q1[2]));
    float S = q0[1] * exp2f((q0[0] - n) * Kc);
    S = fmaf(q0[3], exp2f((q0[2] - n) * Kc), S);
    S = fmaf(q1[1], exp2f((q1[0] - n) * Kc), S);
    S = fmaf(q1[3], exp2f((q1[2] - n) * Kc), S);

    const int raw = target[idx];
    const bool valid = (raw != -1);
    const int lbl = valid ? raw : 0;
    const float wl = logits[(size_t)(b * C_ + lbl) * T_ + t];

    // swap the label term exp2((wl-n)K) for exp2((wl-n)K - MM2)
    constexpr float DM = 1.0f - 6.103515625e-06f;  // 1 - 2^-MM2 (MM2 ln2-exact? compute below)
    float el = exp2f((wl - n) * Kc);
    float Smod = fmaf(-el, 1.0f - exp2f(-MM2), S);
    (void)DM;
    Smod = fmaxf(Smod, 1e-35f);

    float L = (fmaf(wl - n, Kc, -MM2) - log2f(Smod)) * LN2f;
    float contrib = valid ? -L : 0.f;
    float cnt = valid ? 1.f : 0.f;

    #pragma unroll
    for (int off = 32; off; off >>= 1) {
        contrib += __shfl_down(contrib, off);
        cnt     += __shfl_down(cnt, off);
    }

    __shared__ float wsum[8], wcnt[8];
    const int lane = threadIdx.x & 63, w = threadIdx.x >> 6;
    if (lane == 0) { wsum[w] = contrib; wcnt[w] = cnt; }
    __syncthreads();

    if (threadIdx.x == 0) {
        float cs_ = 0.f, cc = 0.f;
        #pragma unroll
        for (int k = 0; k < 8; ++k) { cs_ += wsum[k]; cc += wcnt[k]; }
        const int bb = blockIdx.x >> 4;   // 16 blocks per b
        atomicAdd(&accum[bb], cs_);
        atomicAdd(&accum[4 + bb], cc);
        __threadfence();
        const unsigned old = atomicAdd(done, 1u);
        if (old == (unsigned)(nblocks - 1)) {
            float acc = 0.f;
            #pragma unroll
            for (int k = 0; k < B_; ++k) {
                const float ss = atomicAdd(&accum[k], 0.f);
                const float sc = atomicAdd(&accum[4 + k], 0.f);
                acc += ss / sc;
            }
            out[0] = acc * (1.0f / (float)B_);
        }
    }
}

extern "C" void kernel_launch(void* const* d_in, const int* in_sizes, int n_in,
                              void* d_out, int out_size, void* d_ws, size_t ws_size,
                              hipStream_t stream) {
    const float* logits = (const float*)d_in[0];
    const int*   target = (const int*)d_in[1];
    float*    out     = (float*)d_out;
    float2*   partial = (float2*)((char*)d_ws + WS_PARTIAL);
    float*    accum   = (float*)((char*)d_ws + WS_ACC);
    unsigned* done    = (unsigned*)((char*)d_ws + WS_DONE);

    hipMemsetAsync((char*)d_ws + WS_ACC, 0, 8 * sizeof(float) + sizeof(unsigned), stream);

    adms_partial<<<B_ * 32 * CS, 512, 0, stream>>>(logits, partial);

    const int nb2 = (B_ * T_) / 512;   // 64
    adms_merge<<<nb2, 512, 0, stream>>>(logits, target, partial, accum, done, out, nb2);
}

// Round 4
// 61.315 us; speedup vs baseline: 1.1299x; 1.0086x over previous
//
#include <hip/hip_runtime.h>
#include <math.h>

#define B_ 4
#define C_ 2048
#define T_ 8192
#define CS 4                 // C-splits per (b, t-tile)
#define TILE_T 256           // t columns per block = 64 lanes * float4
#define NW 8                 // waves per block (512 threads)
#define CROWS (C_ / CS)      // 512 rows per block
#define ROWS_W (CROWS / NW)  // 64 rows per thread

typedef float f4 __attribute__((ext_vector_type(4)));

#define NPART (B_ * T_ * CS)            // 131072 f4 entries = 2 MiB
#define WS_ACC ((size_t)NPART * 16)
#define WS_DONE (WS_ACC + 8 * 4)

constexpr float Kc   = 30.0f * 1.4426950408889634f;          // S*log2(e)
constexpr float MM2  = 30.0f * 0.4f * 1.4426950408889634f;   // S*M*log2(e)
constexpr float LN2f = 0.6931471805599453f;

// K1: per (b, t-tile, c-chunk): partial lse (m,S) + label-logit wl.
// Double-buffered float4 loads: next 8 rows in flight during compute.
__global__ __launch_bounds__(512, 4)
void adms_partial(const float* __restrict__ logits,
                  const int* __restrict__ target,
                  f4* __restrict__ partial,
                  float* __restrict__ accum,
                  unsigned* __restrict__ done)
{
    if (blockIdx.x == 0 && threadIdx.x == 0) {
        #pragma unroll
        for (int k = 0; k < 8; ++k) accum[k] = 0.f;
        *done = 0u;
    }

    const int lane = threadIdx.x & 63;
    const int w    = threadIdx.x >> 6;
    const int cs = blockIdx.x & (CS - 1);
    const int tt = (blockIdx.x >> 2) & 31;
    const int b  = blockIdx.x >> 7;

    const int t0 = tt * TILE_T + lane * 4;
    const int c0 = cs * CROWS + w * ROWS_W;
    const float* p = logits + (size_t)(b * C_ + c0) * T_ + t0;

    const int4 l4 = *(const int4*)(target + b * T_ + t0);
    const int lbl[4] = {l4.x, l4.y, l4.z, l4.w};

    float m[4]   = {-INFINITY, -INFINITY, -INFINITY, -INFINITY};
    float s[4]   = {0.f, 0.f, 0.f, 0.f};
    float wlr[4] = {-INFINITY, -INFINITY, -INFINITY, -INFINITY};

    auto load = [&](f4* v, int rbase) {
        #pragma unroll
        for (int i = 0; i < 8; ++i)
            v[i] = *(const f4*)(p + (size_t)(rbase + i) * T_);
    };
    auto compute = [&](const f4* v, int rbase) {
        #pragma unroll
        for (int j = 0; j < 4; ++j) {
            float g = fmaxf(fmaxf(fmaxf(v[0][j], v[1][j]), fmaxf(v[2][j], v[3][j])),
                            fmaxf(fmaxf(v[4][j], v[5][j]), fmaxf(v[6][j], v[7][j])));
            float gK = g * Kc;
            float ps = 0.f;
            #pragma unroll
            for (int i = 0; i < 8; ++i)
                ps += exp2f(fmaf(v[i][j], Kc, -gK));
            float n = fmaxf(m[j], g);
            s[j] = fmaf(s[j], exp2f((m[j] - n) * Kc), ps * exp2f((g - n) * Kc));
            m[j] = n;
            #pragma unroll
            for (int i = 0; i < 8; ++i)
                if (c0 + rbase + i == lbl[j]) wlr[j] = v[i][j];
        }
    };

    f4 va[8], vb[8];
    load(va, 0);
    for (int r = 0; r < ROWS_W - 16; r += 16) {
        load(vb, r + 8);
        compute(va, r);
        load(va, r + 16);
        compute(vb, r + 8);
    }
    load(vb, ROWS_W - 8);
    compute(va, ROWS_W - 16);
    compute(vb, ROWS_W - 8);

    __shared__ float lds_m[NW][TILE_T];
    __shared__ float lds_s[NW][TILE_T];
    __shared__ float lds_w[NW][TILE_T];
    #pragma unroll
    for (int j = 0; j < 4; ++j) {
        lds_m[w][lane * 4 + j] = m[j];
        lds_s[w][lane * 4 + j] = s[j];
        lds_w[w][lane * 4 + j] = wlr[j];
    }
    __syncthreads();

    if (threadIdx.x < TILE_T) {
        const int tc = threadIdx.x;
        float M = -INFINITY, WL = -INFINITY;
        #pragma unroll
        for (int k = 0; k < NW; ++k) {
            M  = fmaxf(M,  lds_m[k][tc]);
            WL = fmaxf(WL, lds_w[k][tc]);
        }
        float S = 0.f;
        #pragma unroll
        for (int k = 0; k < NW; ++k)
            S = fmaf(lds_s[k][tc], exp2f((lds_m[k][tc] - M) * Kc), S);
        f4 o; o[0] = M; o[1] = S; o[2] = WL; o[3] = 0.f;
        partial[((size_t)(b << 13) + tt * TILE_T + tc) * CS + cs] = o;
    }
}

// K2: merge CS partials per (b,t), margin fixup, reduce, finalize.
__global__ __launch_bounds__(256)
void adms_merge(const int* __restrict__ target,
                const f4* __restrict__ partial,
                float* __restrict__ accum,
                unsigned* __restrict__ done,
                float* __restrict__ out,
                int nblocks)
{
    const int idx = blockIdx.x * 256 + threadIdx.x;   // 0..32767

    const f4* pf = partial + (size_t)idx * CS;
    f4 q0 = pf[0], q1 = pf[1], q2 = pf[2], q3 = pf[3];

    float n = fmaxf(fmaxf(q0[0], q1[0]), fmaxf(q2[0], q3[0]));
    float S = q0[1] * exp2f((q0[0] - n) * Kc);
    S = fmaf(q1[1], exp2f((q1[0] - n) * Kc), S);
    S = fmaf(q2[1], exp2f((q2[0] - n) * Kc), S);
    S = fmaf(q3[1], exp2f((q3[0] - n) * Kc), S);
    float wl = fmaxf(fmaxf(q0[2], q1[2]), fmaxf(q2[2], q3[2]));

    const int raw = target[idx];
    const bool valid = (raw != -1);

    // swap label term exp2((wl-n)K) for exp2((wl-n)K - MM2)
    float el = exp2f((wl - n) * Kc);
    float Smod = fmaf(-el, 1.0f - exp2f(-MM2), S);
    Smod = fmaxf(Smod, 1e-35f);
    float L = (fmaf(wl - n, Kc, -MM2) - log2f(Smod)) * LN2f;

    float contrib = valid ? -L : 0.f;
    float cnt     = valid ? 1.f : 0.f;
    #pragma unroll
    for (int off = 32; off; off >>= 1) {
        contrib += __shfl_down(contrib, off);
        cnt     += __shfl_down(cnt, off);
    }

    __shared__ float wsum[4], wcnt[4];
    const int lane = threadIdx.x & 63, w = threadIdx.x >> 6;
    if (lane == 0) { wsum[w] = contrib; wcnt[w] = cnt; }
    __syncthreads();

    if (threadIdx.x == 0) {
        float cs_ = 0.f, cc = 0.f;
        #pragma unroll
        for (int k = 0; k < 4; ++k) { cs_ += wsum[k]; cc += wcnt[k]; }
        const int bb = blockIdx.x >> 5;   // 32 blocks per b
        atomicAdd(&accum[bb], cs_);
        atomicAdd(&accum[4 + bb], cc);
        __threadfence();
        const unsigned old = atomicAdd(done, 1u);
        if (old == (unsigned)(nblocks - 1)) {
            float acc = 0.f;
            #pragma unroll
            for (int k = 0; k < B_; ++k) {
                const float ss = atomicAdd(&accum[k], 0.f);
                const float sc = atomicAdd(&accum[4 + k], 0.f);
                acc += ss / sc;
            }
            out[0] = acc * (1.0f / (float)B_);
        }
    }
}

extern "C" void kernel_launch(void* const* d_in, const int* in_sizes, int n_in,
                              void* d_out, int out_size, void* d_ws, size_t ws_size,
                              hipStream_t stream) {
    const float* logits = (const float*)d_in[0];
    const int*   target = (const int*)d_in[1];
    float*    out     = (float*)d_out;
    f4*       partial = (f4*)d_ws;
    float*    accum   = (float*)((char*)d_ws + WS_ACC);
    unsigned* done    = (unsigned*)((char*)d_ws + WS_DONE);

    adms_partial<<<B_ * 32 * CS, 512, 0, stream>>>(logits, target, partial, accum, done);

    const int nb2 = (B_ * T_) / 256;   // 128
    adms_merge<<<nb2, 256, 0, stream>>>(target, partial, accum, done, out, nb2);
}